// Round 10
// baseline (106.320 us; speedup 1.0000x reference)
//
#include <hip/hip_runtime.h>
#include <math.h>

#define DD 128
#define HH 128
#define WW 128
#define NN (DD*HH*WW)
#define DJ 127

// workspace layout: [slots: doubles][bwd interleaved float4 volume]
#define NB_LNCC 4096
#define NB_FUSED 8192
#define LOFF 0
#define GOFF (NB_LNCC)
#define JOFF (NB_LNCC + NB_FUSED)
#define IOFF (NB_LNCC + 2*NB_FUSED)
#define NSLOTS (NB_LNCC + 3*NB_FUSED)
#define BWDI_OFF ((size_t)((NSLOTS * 8 + 255) & ~255))   // 256B aligned
#define WS_NEED (BWDI_OFF + (size_t)NN * 16)

// ---------- small helpers ----------
__device__ __forceinline__ double wave_reduce(double v) {
    #pragma unroll
    for (int o = 32; o > 0; o >>= 1) v += __shfl_down(v, o);
    return v;
}

template <int NWAVES>
__device__ __forceinline__ double block_reduce(double v, double* red, int tid) {
    v = wave_reduce(v);
    int wid = tid >> 6, lane = tid & 63;
    __syncthreads();
    if (lane == 0) red[wid] = v;
    __syncthreads();
    double x = 0.0;
    if (tid == 0) {
        #pragma unroll
        for (int w = 0; w < NWAVES; w++) x += red[w];
    }
    return x;
}

__device__ __forceinline__ float4 add4(float4 a, float4 b) {
    return make_float4(a.x + b.x, a.y + b.y, a.z + b.z, a.w + b.w);
}

__device__ __forceinline__ float jac_term(const float* dz_, const float* dy_, const float* dx_) {
    float a00 = 1.f + dz_[0], a01 = dy_[0], a02 = dx_[0];
    float a10 = dz_[1], a11 = 1.f + dy_[1], a12 = dx_[1];
    float a20 = dz_[2], a21 = dy_[2], a22 = 1.f + dx_[2];
    float det = a00 * (a11 * a22 - a12 * a21)
              - a01 * (a10 * a22 - a12 * a20)
              + a02 * (a10 * a21 - a11 * a20);
    if (isnan(det)) det = 0.f;
    else if (isinf(det)) det = det > 0.f ? 1000.f : -1000.f;
    float neg = -det;
    return neg > 0.f ? neg : 0.f;
}

// ---------- 0) channel-interleave bwd -> bwdi, 4 voxels/thread ----------
__global__ __launch_bounds__(256) void interleave4_kernel(const float* __restrict__ bwd,
                                                          float4* __restrict__ bwdi) {
    const int i4 = (blockIdx.x * 256 + threadIdx.x) * 4;
    float4 b0 = *(const float4*)(bwd + i4);
    float4 b1 = *(const float4*)(bwd + NN + i4);
    float4 b2 = *(const float4*)(bwd + 2 * NN + i4);
    bwdi[i4 + 0] = make_float4(b0.x, b1.x, b2.x, 0.f);
    bwdi[i4 + 1] = make_float4(b0.y, b1.y, b2.y, 0.f);
    bwdi[i4 + 2] = make_float4(b0.z, b1.z, b2.z, 0.f);
    bwdi[i4 + 3] = make_float4(b0.w, b1.w, b2.w, 0.f);
}

// ---------- 1) LNCC core (separable box filter, vector LDS; r7-proven ~25us) ----------
__global__ __launch_bounds__(512) void lncc_kernel(const float* __restrict__ src,
                                                   const float* __restrict__ tgt,
                                                   double* __restrict__ ws) {
    __shared__ __align__(16) float F1[5][12 * 12 * 8];   // x-summed moments
    __shared__ __align__(16) float F2[5][12 * 8 * 8];    // xy-summed moments
    __shared__ double red[8];
    const int tid = threadIdx.x;
    const int slot = (blockIdx.x & 7) * 512 + (blockIdx.x >> 3);   // bijective, 4096%8==0
    const int bz = (slot >> 8) * 8;
    const int by = ((slot >> 4) & 15) * 8;
    const int bx = (slot & 15) * 8;

    // ---- x-pass: one half-row (4 outputs) per thread, 288 tasks ----
    if (tid < 288) {
        const int h = tid & 1;
        const int row = tid >> 1;
        const int ly = row % 12, lz = row / 12;
        const int gy = by + ly - 2, gz = bz + lz - 2;
        const bool rowok = (gy >= 0 && gy < HH && gz >= 0 && gz < DD);
        const int rowbase = (gz * HH + gy) * WW;
        const int w0 = bx + h * 4 - 4;            // aligned float4 window start

        float4 lsv[3], ltv[3];
        #pragma unroll
        for (int p = 0; p < 3; p++) {
            int gx = w0 + 4 * p;
            if (rowok && gx >= 0 && gx <= WW - 4) {
                lsv[p] = *(const float4*)(src + rowbase + gx);
                ltv[p] = *(const float4*)(tgt + rowbase + gx);
            } else {
                lsv[p] = make_float4(0.f, 0.f, 0.f, 0.f);
                ltv[p] = make_float4(0.f, 0.f, 0.f, 0.f);
            }
        }
        const float* ls = (const float*)lsv;   // 12 values, static-indexed below
        const float* lt = (const float*)ltv;

        float o[5][4];
        #pragma unroll
        for (int k = 0; k < 4; k++) {
            float s1 = 0.f, t1s = 0.f, s2 = 0.f, t2s = 0.f, st = 0.f;
            #pragma unroll
            for (int d = 0; d < 5; d++) {
                float a = ls[k + d + 2], b = lt[k + d + 2];
                s1 += a; t1s += b;
                s2 = fmaf(a, a, s2); t2s = fmaf(b, b, t2s); st = fmaf(a, b, st);
            }
            o[0][k] = s1; o[1][k] = t1s; o[2][k] = s2; o[3][k] = t2s; o[4][k] = st;
        }
        const int obase = (lz * 12 + ly) * 8 + h * 4;
        #pragma unroll
        for (int f = 0; f < 5; f++)
            *(float4*)&F1[f][obase] = make_float4(o[f][0], o[f][1], o[f][2], o[f][3]);
    }
    __syncthreads();

    // ---- y-pass: 4 outputs per thread, 192 tasks ----
    if (tid < 192) {
        const int h = tid & 1;
        const int r = tid >> 1;
        const int oy = r & 7, lz = r >> 3;
        float4 a0 = make_float4(0.f, 0.f, 0.f, 0.f), a1 = a0, a2 = a0, a3 = a0, a4 = a0;
        #pragma unroll
        for (int dy = 0; dy < 5; dy++) {
            const int j = (lz * 12 + oy + dy) * 8 + h * 4;
            a0 = add4(a0, *(const float4*)&F1[0][j]);
            a1 = add4(a1, *(const float4*)&F1[1][j]);
            a2 = add4(a2, *(const float4*)&F1[2][j]);
            a3 = add4(a3, *(const float4*)&F1[3][j]);
            a4 = add4(a4, *(const float4*)&F1[4][j]);
        }
        const int jo = (lz * 8 + oy) * 8 + h * 4;
        *(float4*)&F2[0][jo] = a0;
        *(float4*)&F2[1][jo] = a1;
        *(float4*)&F2[2][jo] = a2;
        *(float4*)&F2[3][jo] = a3;
        *(float4*)&F2[4][jo] = a4;
    }
    __syncthreads();

    // ---- z-pass + lncc: 4 voxels per thread, 128 tasks ----
    double lsum = 0.0;
    if (tid < 128) {
        const int h = tid & 1;
        const int r = tid >> 1;
        const int oy = r & 7, oz = r >> 3;
        float A[5][4];
        #pragma unroll
        for (int f = 0; f < 5; f++) { A[f][0] = A[f][1] = A[f][2] = A[f][3] = 0.f; }
        #pragma unroll
        for (int dz = 0; dz < 5; dz++) {
            const int j = ((oz + dz) * 8 + oy) * 8 + h * 4;
            #pragma unroll
            for (int f = 0; f < 5; f++) {
                float4 q = *(const float4*)&F2[f][j];
                A[f][0] += q.x; A[f][1] += q.y; A[f][2] += q.z; A[f][3] += q.w;
            }
        }
        const float inv125 = 1.f / 125.f;
        #pragma unroll
        for (int k = 0; k < 4; k++) {
            float sm = A[0][k] * inv125, tm = A[1][k] * inv125;
            float sv = A[2][k] * inv125 - sm * sm;
            float tv = A[3][k] * inv125 - tm * tm;
            float cross = A[4][k] * inv125 - sm * tm;
            float l = cross * cross / (sv * tv + 1e-5f);
            lsum += (double)l;
        }
    }
    double tot = block_reduce<8>(lsum, red, tid);
    if (tid == 0) ws[LOFF + slot] = tot;
}

// ---------- 2) fused grad + jac + inv: 1 voxel/thread, LANE-CONSECUTIVE x ----------
// The gather-divergence fix: adjacent lanes process adjacent x, so a wave's 64
// corner gathers span ~1KB contiguous (+flow jitter) => ~16-20 cache lines per
// instruction instead of 64 (all prior variants put lanes 2-4 voxels apart =
// one distinct line per lane). Same instruction count (8 float4/voxel).
// Medium concurrency (16 waves/CU) + XCD-z-slab swizzle: per-XCD live window
// stays well under the 4MB L2 (r7's thrash was 22 waves/CU with 64-line instrs).
__global__ __launch_bounds__(256, 4) void fused1_kernel(const float* __restrict__ fwd,
                                                        const float4* __restrict__ bwdi,
                                                        double* __restrict__ ws) {
    __shared__ double red[4];

    const int swz = (blockIdx.x & 7) * (NB_FUSED / 8) + (blockIdx.x >> 3);  // bijective, 8192%8==0
    const int idx = swz * 256 + threadIdx.x;        // voxel id; z-slab [16*(bid&7),...+16)
    const int x = idx & 127; const int y = (idx >> 7) & 127; const int z = idx >> 14;
    const bool hx = (x < WW - 1), hy = (y < HH - 1), hz = (z < DD - 1);

    double accG = 0.0, accJ = 0.0, accI = 0.0;

    // ---- fwd loads: scalar, perfectly coalesced (lane-consecutive) ----
    float v[3], ddx[3], ddy[3], ddz[3];
    #pragma unroll
    for (int c = 0; c < 3; c++) {
        const float* p = fwd + c * NN + idx;
        float vv = p[0];
        v[c]   = vv;
        ddx[c] = hx ? (p[1] - vv) : 0.f;
        ddy[c] = hy ? (p[WW] - vv) : 0.f;
        ddz[c] = hz ? (p[HH * WW] - vv) : 0.f;
    }

    // grad3d L2
    {
        float g = 0.f;
        #pragma unroll
        for (int c = 0; c < 3; c++)
            g = fmaf(ddz[c], ddz[c], fmaf(ddy[c], ddy[c], fmaf(ddx[c], ddx[c], g)));
        accG = (double)g;
    }

    // negative Jacobian (interior 127^3)
    if (hx && hy && hz) accJ = (double)jac_term(ddz, ddy, ddx);

    // inverse consistency via interleaved float4 gathers
    {
        float cz = fminf(fmaxf((float)z + v[0], 0.f), (float)(DD - 1));
        float cy = fminf(fmaxf((float)y + v[1], 0.f), (float)(HH - 1));
        float cx = fminf(fmaxf((float)x + v[2], 0.f), (float)(WW - 1));
        float z0f = floorf(cz), y0f = floorf(cy), x0f = floorf(cx);
        float fz = cz - z0f, fy = cy - y0f, fx = cx - x0f;
        int z0 = (int)z0f, y0 = (int)y0f, x0 = (int)x0f;
        int z1 = min(z0 + 1, DD - 1), y1 = min(y0 + 1, HH - 1), x1 = min(x0 + 1, WW - 1);
        int b00 = (z0 * HH + y0) * WW, b01 = (z0 * HH + y1) * WW;
        int b10 = (z1 * HH + y0) * WW, b11 = (z1 * HH + y1) * WW;
        float4 C000 = bwdi[b00 + x0], C001 = bwdi[b00 + x1];
        float4 C010 = bwdi[b01 + x0], C011 = bwdi[b01 + x1];
        float4 C100 = bwdi[b10 + x0], C101 = bwdi[b10 + x1];
        float4 C110 = bwdi[b11 + x0], C111 = bwdi[b11 + x1];
        float w000 = (1.f - fz) * (1.f - fy) * (1.f - fx);
        float w001 = (1.f - fz) * (1.f - fy) * fx;
        float w010 = (1.f - fz) * fy * (1.f - fx);
        float w011 = (1.f - fz) * fy * fx;
        float w100 = fz * (1.f - fy) * (1.f - fx);
        float w101 = fz * (1.f - fy) * fx;
        float w110 = fz * fy * (1.f - fx);
        float w111 = fz * fy * fx;
        float c0 = v[0] + w000 * C000.x + w001 * C001.x + w010 * C010.x + w011 * C011.x
                        + w100 * C100.x + w101 * C101.x + w110 * C110.x + w111 * C111.x;
        float c1 = v[1] + w000 * C000.y + w001 * C001.y + w010 * C010.y + w011 * C011.y
                        + w100 * C100.y + w101 * C101.y + w110 * C110.y + w111 * C111.y;
        float c2 = v[2] + w000 * C000.z + w001 * C001.z + w010 * C010.z + w011 * C011.z
                        + w100 * C100.z + w101 * C101.z + w110 * C110.z + w111 * C111.z;
        accI = (double)(c0 * c0 + c1 * c1 + c2 * c2);
    }

    double tG = block_reduce<4>(accG, red, threadIdx.x);
    double tJ = block_reduce<4>(accJ, red, threadIdx.x);
    double tI = block_reduce<4>(accI, red, threadIdx.x);
    if (threadIdx.x == 0) {
        ws[GOFF + swz] = tG;
        ws[JOFF + swz] = tJ;
        ws[IOFF + swz] = tI;
    }
}

// ---------- 2b) fallback: same structure, planar scalar gathers ----------
__global__ __launch_bounds__(256) void fused_fallback(const float* __restrict__ fwd,
                                                      const float* __restrict__ bwd,
                                                      double* __restrict__ ws) {
    __shared__ double red[4];
    const int idx = blockIdx.x * 256 + threadIdx.x;
    const int x = idx & 127; const int y = (idx >> 7) & 127; const int z = idx >> 14;
    const bool hx = (x < WW - 1), hy = (y < HH - 1), hz = (z < DD - 1);

    double accG = 0.0, accJ = 0.0, accI = 0.0;
    float v[3], ddx[3], ddy[3], ddz[3];
    #pragma unroll
    for (int c = 0; c < 3; c++) {
        const float* p = fwd + c * NN + idx;
        float vv = p[0];
        v[c]   = vv;
        ddx[c] = hx ? (p[1] - vv) : 0.f;
        ddy[c] = hy ? (p[WW] - vv) : 0.f;
        ddz[c] = hz ? (p[HH * WW] - vv) : 0.f;
    }
    float g = 0.f;
    #pragma unroll
    for (int c = 0; c < 3; c++)
        g = fmaf(ddz[c], ddz[c], fmaf(ddy[c], ddy[c], fmaf(ddx[c], ddx[c], g)));
    accG = (double)g;
    if (hx && hy && hz) accJ = (double)jac_term(ddz, ddy, ddx);
    {
        float cz = fminf(fmaxf((float)z + v[0], 0.f), (float)(DD - 1));
        float cy = fminf(fmaxf((float)y + v[1], 0.f), (float)(HH - 1));
        float cx = fminf(fmaxf((float)x + v[2], 0.f), (float)(WW - 1));
        float z0f = floorf(cz), y0f = floorf(cy), x0f = floorf(cx);
        float fz = cz - z0f, fy = cy - y0f, fx = cx - x0f;
        int z0 = (int)z0f, y0 = (int)y0f, x0 = (int)x0f;
        int z1 = min(z0 + 1, DD - 1), y1 = min(y0 + 1, HH - 1), x1 = min(x0 + 1, WW - 1);
        int i000 = (z0 * HH + y0) * WW + x0, i001 = (z0 * HH + y0) * WW + x1;
        int i010 = (z0 * HH + y1) * WW + x0, i011 = (z0 * HH + y1) * WW + x1;
        int i100 = (z1 * HH + y0) * WW + x0, i101 = (z1 * HH + y0) * WW + x1;
        int i110 = (z1 * HH + y1) * WW + x0, i111 = (z1 * HH + y1) * WW + x1;
        float w000 = (1.f - fz) * (1.f - fy) * (1.f - fx);
        float w001 = (1.f - fz) * (1.f - fy) * fx;
        float w010 = (1.f - fz) * fy * (1.f - fx);
        float w011 = (1.f - fz) * fy * fx;
        float w100 = fz * (1.f - fy) * (1.f - fx);
        float w101 = fz * (1.f - fy) * fx;
        float w110 = fz * fy * (1.f - fx);
        float w111 = fz * fy * fx;
        #pragma unroll
        for (int c = 0; c < 3; c++) {
            const float* b = bwd + c * NN;
            float warped = w000 * b[i000] + w001 * b[i001]
                         + w010 * b[i010] + w011 * b[i011]
                         + w100 * b[i100] + w101 * b[i101]
                         + w110 * b[i110] + w111 * b[i111];
            float comp = v[c] + warped;
            accI += (double)(comp * comp);
        }
    }

    double tG = block_reduce<4>(accG, red, threadIdx.x);
    double tJ = block_reduce<4>(accJ, red, threadIdx.x);
    double tI = block_reduce<4>(accI, red, threadIdx.x);
    if (threadIdx.x == 0) {
        ws[GOFF + blockIdx.x] = tG;
        ws[JOFF + blockIdx.x] = tJ;
        ws[IOFF + blockIdx.x] = tI;
    }
}

// ---------- 3) finalize ----------
__global__ __launch_bounds__(256) void finalize_kernel(const double* __restrict__ ws,
                                                       float* __restrict__ out) {
    __shared__ double red[4];
    double l = 0.0, g = 0.0, j = 0.0, inv = 0.0;
    for (int k = threadIdx.x; k < NB_LNCC; k += 256) l += ws[LOFF + k];
    for (int k = threadIdx.x; k < NB_FUSED; k += 256) {
        g   += ws[GOFF + k];
        j   += ws[JOFF + k];
        inv += ws[IOFF + k];
    }
    double tl = block_reduce<4>(l, red, threadIdx.x);
    double tg = block_reduce<4>(g, red, threadIdx.x);
    double tj = block_reduce<4>(j, red, threadIdx.x);
    double ti = block_reduce<4>(inv, red, threadIdx.x);
    if (threadIdx.x == 0) {
        double li = 1.0 - tl / (double)NN;
        if (isnan(li) || isinf(li)) li = 1.0;
        double grad = tg / (9.0 * 127.0 * 128.0 * 128.0);
        double jac  = tj / ((double)DJ * DJ * DJ);
        double iv = ti / (3.0 * (double)NN);
        if (isnan(iv)) iv = 0.0;
        else if (isinf(iv)) iv = iv > 0.0 ? 1000.0 : 0.0;
        out[0] = (float)(1.0 * li + 0.02 * grad + 0.01 * jac + 0.1 * iv);
    }
}

extern "C" void kernel_launch(void* const* d_in, const int* in_sizes, int n_in,
                              void* d_out, int out_size, void* d_ws, size_t ws_size,
                              hipStream_t stream) {
    const float* src = (const float*)d_in[0];
    const float* tgt = (const float*)d_in[1];
    const float* fwd = (const float*)d_in[2];
    const float* bwd = (const float*)d_in[3];
    double* ws = (double*)d_ws;
    float* out = (float*)d_out;

    if (ws_size >= WS_NEED) {
        float4* bwdi = (float4*)((char*)d_ws + BWDI_OFF);
        interleave4_kernel<<<2048, 256, 0, stream>>>(bwd, bwdi);
        lncc_kernel<<<4096, 512, 0, stream>>>(src, tgt, ws);
        fused1_kernel<<<NB_FUSED, 256, 0, stream>>>(fwd, bwdi, ws);
    } else {
        lncc_kernel<<<4096, 512, 0, stream>>>(src, tgt, ws);
        fused_fallback<<<NB_FUSED, 256, 0, stream>>>(fwd, bwd, ws);
    }
    finalize_kernel<<<1, 256, 0, stream>>>(ws, out);
}

// Round 11
// 90.635 us; speedup vs baseline: 1.1731x; 1.1731x over previous
//
#include <hip/hip_runtime.h>
#include <hip/hip_fp16.h>
#include <math.h>

#define DD 128
#define HH 128
#define WW 128
#define NN (DD*HH*WW)
#define DJ 127

// workspace layout: [slots: doubles][bwd interleaved half4 volume]
#define NB_LNCC 4096
#define NB_FUSED 8192
#define LOFF 0
#define GOFF (NB_LNCC)
#define JOFF (NB_LNCC + NB_FUSED)
#define IOFF (NB_LNCC + 2*NB_FUSED)
#define NSLOTS (NB_LNCC + 3*NB_FUSED)
#define BWDH_OFF ((size_t)((NSLOTS * 8 + 255) & ~255))   // 256B aligned
#define WS_NEED (BWDH_OFF + (size_t)NN * 8)

struct __align__(8) Half4 { __half x, y, z, w; };

// ---------- small helpers ----------
__device__ __forceinline__ double wave_reduce(double v) {
    #pragma unroll
    for (int o = 32; o > 0; o >>= 1) v += __shfl_down(v, o);
    return v;
}

template <int NWAVES>
__device__ __forceinline__ double block_reduce(double v, double* red, int tid) {
    v = wave_reduce(v);
    int wid = tid >> 6, lane = tid & 63;
    __syncthreads();
    if (lane == 0) red[wid] = v;
    __syncthreads();
    double x = 0.0;
    if (tid == 0) {
        #pragma unroll
        for (int w = 0; w < NWAVES; w++) x += red[w];
    }
    return x;
}

__device__ __forceinline__ float4 add4(float4 a, float4 b) {
    return make_float4(a.x + b.x, a.y + b.y, a.z + b.z, a.w + b.w);
}

__device__ __forceinline__ float jac_term(const float* dz_, const float* dy_, const float* dx_) {
    float a00 = 1.f + dz_[0], a01 = dy_[0], a02 = dx_[0];
    float a10 = dz_[1], a11 = 1.f + dy_[1], a12 = dx_[1];
    float a20 = dz_[2], a21 = dy_[2], a22 = 1.f + dx_[2];
    float det = a00 * (a11 * a22 - a12 * a21)
              - a01 * (a10 * a22 - a12 * a20)
              + a02 * (a10 * a21 - a11 * a20);
    if (isnan(det)) det = 0.f;
    else if (isinf(det)) det = det > 0.f ? 1000.f : -1000.f;
    float neg = -det;
    return neg > 0.f ? neg : 0.f;
}

// ---------- 0) channel-interleave bwd -> half4 bwdh, 4 voxels/thread ----------
__global__ __launch_bounds__(256) void interleave4h_kernel(const float* __restrict__ bwd,
                                                           Half4* __restrict__ bwdh) {
    const int i4 = (blockIdx.x * 256 + threadIdx.x) * 4;
    float4 b0 = *(const float4*)(bwd + i4);
    float4 b1 = *(const float4*)(bwd + NN + i4);
    float4 b2 = *(const float4*)(bwd + 2 * NN + i4);
    Half4 o0 = { __float2half(b0.x), __float2half(b1.x), __float2half(b2.x), __float2half(0.f) };
    Half4 o1 = { __float2half(b0.y), __float2half(b1.y), __float2half(b2.y), __float2half(0.f) };
    Half4 o2 = { __float2half(b0.z), __float2half(b1.z), __float2half(b2.z), __float2half(0.f) };
    Half4 o3 = { __float2half(b0.w), __float2half(b1.w), __float2half(b2.w), __float2half(0.f) };
    bwdh[i4 + 0] = o0;
    bwdh[i4 + 1] = o1;
    bwdh[i4 + 2] = o2;
    bwdh[i4 + 3] = o3;
}

// ---------- 1) LNCC core (separable box filter, vector LDS; r7-proven ~25us) ----------
__global__ __launch_bounds__(512) void lncc_kernel(const float* __restrict__ src,
                                                   const float* __restrict__ tgt,
                                                   double* __restrict__ ws) {
    __shared__ __align__(16) float F1[5][12 * 12 * 8];   // x-summed moments
    __shared__ __align__(16) float F2[5][12 * 8 * 8];    // xy-summed moments
    __shared__ double red[8];
    const int tid = threadIdx.x;
    const int slot = (blockIdx.x & 7) * 512 + (blockIdx.x >> 3);   // bijective, 4096%8==0
    const int bz = (slot >> 8) * 8;
    const int by = ((slot >> 4) & 15) * 8;
    const int bx = (slot & 15) * 8;

    // ---- x-pass: one half-row (4 outputs) per thread, 288 tasks ----
    if (tid < 288) {
        const int h = tid & 1;
        const int row = tid >> 1;
        const int ly = row % 12, lz = row / 12;
        const int gy = by + ly - 2, gz = bz + lz - 2;
        const bool rowok = (gy >= 0 && gy < HH && gz >= 0 && gz < DD);
        const int rowbase = (gz * HH + gy) * WW;
        const int w0 = bx + h * 4 - 4;            // aligned float4 window start

        float4 lsv[3], ltv[3];
        #pragma unroll
        for (int p = 0; p < 3; p++) {
            int gx = w0 + 4 * p;
            if (rowok && gx >= 0 && gx <= WW - 4) {
                lsv[p] = *(const float4*)(src + rowbase + gx);
                ltv[p] = *(const float4*)(tgt + rowbase + gx);
            } else {
                lsv[p] = make_float4(0.f, 0.f, 0.f, 0.f);
                ltv[p] = make_float4(0.f, 0.f, 0.f, 0.f);
            }
        }
        const float* ls = (const float*)lsv;   // 12 values, static-indexed below
        const float* lt = (const float*)ltv;

        float o[5][4];
        #pragma unroll
        for (int k = 0; k < 4; k++) {
            float s1 = 0.f, t1s = 0.f, s2 = 0.f, t2s = 0.f, st = 0.f;
            #pragma unroll
            for (int d = 0; d < 5; d++) {
                float a = ls[k + d + 2], b = lt[k + d + 2];
                s1 += a; t1s += b;
                s2 = fmaf(a, a, s2); t2s = fmaf(b, b, t2s); st = fmaf(a, b, st);
            }
            o[0][k] = s1; o[1][k] = t1s; o[2][k] = s2; o[3][k] = t2s; o[4][k] = st;
        }
        const int obase = (lz * 12 + ly) * 8 + h * 4;
        #pragma unroll
        for (int f = 0; f < 5; f++)
            *(float4*)&F1[f][obase] = make_float4(o[f][0], o[f][1], o[f][2], o[f][3]);
    }
    __syncthreads();

    // ---- y-pass: 4 outputs per thread, 192 tasks ----
    if (tid < 192) {
        const int h = tid & 1;
        const int r = tid >> 1;
        const int oy = r & 7, lz = r >> 3;
        float4 a0 = make_float4(0.f, 0.f, 0.f, 0.f), a1 = a0, a2 = a0, a3 = a0, a4 = a0;
        #pragma unroll
        for (int dy = 0; dy < 5; dy++) {
            const int j = (lz * 12 + oy + dy) * 8 + h * 4;
            a0 = add4(a0, *(const float4*)&F1[0][j]);
            a1 = add4(a1, *(const float4*)&F1[1][j]);
            a2 = add4(a2, *(const float4*)&F1[2][j]);
            a3 = add4(a3, *(const float4*)&F1[3][j]);
            a4 = add4(a4, *(const float4*)&F1[4][j]);
        }
        const int jo = (lz * 8 + oy) * 8 + h * 4;
        *(float4*)&F2[0][jo] = a0;
        *(float4*)&F2[1][jo] = a1;
        *(float4*)&F2[2][jo] = a2;
        *(float4*)&F2[3][jo] = a3;
        *(float4*)&F2[4][jo] = a4;
    }
    __syncthreads();

    // ---- z-pass + lncc: 4 voxels per thread, 128 tasks ----
    double lsum = 0.0;
    if (tid < 128) {
        const int h = tid & 1;
        const int r = tid >> 1;
        const int oy = r & 7, oz = r >> 3;
        float A[5][4];
        #pragma unroll
        for (int f = 0; f < 5; f++) { A[f][0] = A[f][1] = A[f][2] = A[f][3] = 0.f; }
        #pragma unroll
        for (int dz = 0; dz < 5; dz++) {
            const int j = ((oz + dz) * 8 + oy) * 8 + h * 4;
            #pragma unroll
            for (int f = 0; f < 5; f++) {
                float4 q = *(const float4*)&F2[f][j];
                A[f][0] += q.x; A[f][1] += q.y; A[f][2] += q.z; A[f][3] += q.w;
            }
        }
        const float inv125 = 1.f / 125.f;
        #pragma unroll
        for (int k = 0; k < 4; k++) {
            float sm = A[0][k] * inv125, tm = A[1][k] * inv125;
            float sv = A[2][k] * inv125 - sm * sm;
            float tv = A[3][k] * inv125 - tm * tm;
            float cross = A[4][k] * inv125 - sm * tm;
            float l = cross * cross / (sv * tv + 1e-5f);
            lsum += (double)l;
        }
    }
    double tot = block_reduce<8>(lsum, red, tid);
    if (tid == 0) ws[LOFF + slot] = tot;
}

// ---------- 2) fused grad + jac + inv: 1 voxel/thread, half4 gathers ----------
// r10 structure (lane-consecutive x, XCD-z-slab swizzle) with bwdh half4:
// 8 B/corner instead of 16 -> gathered line traffic and bwdh footprint halve
// (16 MB total, 2 MB per XCD slab, well under the 4 MB L2).
__global__ __launch_bounds__(256, 4) void fused1h_kernel(const float* __restrict__ fwd,
                                                         const Half4* __restrict__ bwdh,
                                                         double* __restrict__ ws) {
    __shared__ double red[4];

    const int swz = (blockIdx.x & 7) * (NB_FUSED / 8) + (blockIdx.x >> 3);  // bijective, 8192%8==0
    const int idx = swz * 256 + threadIdx.x;        // voxel id; z-slab [16*(bid&7),...+16)
    const int x = idx & 127; const int y = (idx >> 7) & 127; const int z = idx >> 14;
    const bool hx = (x < WW - 1), hy = (y < HH - 1), hz = (z < DD - 1);

    double accG = 0.0, accJ = 0.0, accI = 0.0;

    // ---- fwd loads: scalar, perfectly coalesced (lane-consecutive) ----
    float v[3], ddx[3], ddy[3], ddz[3];
    #pragma unroll
    for (int c = 0; c < 3; c++) {
        const float* p = fwd + c * NN + idx;
        float vv = p[0];
        v[c]   = vv;
        ddx[c] = hx ? (p[1] - vv) : 0.f;
        ddy[c] = hy ? (p[WW] - vv) : 0.f;
        ddz[c] = hz ? (p[HH * WW] - vv) : 0.f;
    }

    // grad3d L2
    {
        float g = 0.f;
        #pragma unroll
        for (int c = 0; c < 3; c++)
            g = fmaf(ddz[c], ddz[c], fmaf(ddy[c], ddy[c], fmaf(ddx[c], ddx[c], g)));
        accG = (double)g;
    }

    // negative Jacobian (interior 127^3)
    if (hx && hy && hz) accJ = (double)jac_term(ddz, ddy, ddx);

    // inverse consistency via half4 gathers
    {
        float cz = fminf(fmaxf((float)z + v[0], 0.f), (float)(DD - 1));
        float cy = fminf(fmaxf((float)y + v[1], 0.f), (float)(HH - 1));
        float cx = fminf(fmaxf((float)x + v[2], 0.f), (float)(WW - 1));
        float z0f = floorf(cz), y0f = floorf(cy), x0f = floorf(cx);
        float fz = cz - z0f, fy = cy - y0f, fx = cx - x0f;
        int z0 = (int)z0f, y0 = (int)y0f, x0 = (int)x0f;
        int z1 = min(z0 + 1, DD - 1), y1 = min(y0 + 1, HH - 1), x1 = min(x0 + 1, WW - 1);
        int b00 = (z0 * HH + y0) * WW, b01 = (z0 * HH + y1) * WW;
        int b10 = (z1 * HH + y0) * WW, b11 = (z1 * HH + y1) * WW;
        Half4 H000 = bwdh[b00 + x0], H001 = bwdh[b00 + x1];
        Half4 H010 = bwdh[b01 + x0], H011 = bwdh[b01 + x1];
        Half4 H100 = bwdh[b10 + x0], H101 = bwdh[b10 + x1];
        Half4 H110 = bwdh[b11 + x0], H111 = bwdh[b11 + x1];
        float w000 = (1.f - fz) * (1.f - fy) * (1.f - fx);
        float w001 = (1.f - fz) * (1.f - fy) * fx;
        float w010 = (1.f - fz) * fy * (1.f - fx);
        float w011 = (1.f - fz) * fy * fx;
        float w100 = fz * (1.f - fy) * (1.f - fx);
        float w101 = fz * (1.f - fy) * fx;
        float w110 = fz * fy * (1.f - fx);
        float w111 = fz * fy * fx;
        float c0 = v[0] + w000 * __half2float(H000.x) + w001 * __half2float(H001.x)
                        + w010 * __half2float(H010.x) + w011 * __half2float(H011.x)
                        + w100 * __half2float(H100.x) + w101 * __half2float(H101.x)
                        + w110 * __half2float(H110.x) + w111 * __half2float(H111.x);
        float c1 = v[1] + w000 * __half2float(H000.y) + w001 * __half2float(H001.y)
                        + w010 * __half2float(H010.y) + w011 * __half2float(H011.y)
                        + w100 * __half2float(H100.y) + w101 * __half2float(H101.y)
                        + w110 * __half2float(H110.y) + w111 * __half2float(H111.y);
        float c2 = v[2] + w000 * __half2float(H000.z) + w001 * __half2float(H001.z)
                        + w010 * __half2float(H010.z) + w011 * __half2float(H011.z)
                        + w100 * __half2float(H100.z) + w101 * __half2float(H101.z)
                        + w110 * __half2float(H110.z) + w111 * __half2float(H111.z);
        accI = (double)(c0 * c0 + c1 * c1 + c2 * c2);
    }

    double tG = block_reduce<4>(accG, red, threadIdx.x);
    double tJ = block_reduce<4>(accJ, red, threadIdx.x);
    double tI = block_reduce<4>(accI, red, threadIdx.x);
    if (threadIdx.x == 0) {
        ws[GOFF + swz] = tG;
        ws[JOFF + swz] = tJ;
        ws[IOFF + swz] = tI;
    }
}

// ---------- 2b) fallback: same structure, planar scalar gathers (exact fp32) ----------
__global__ __launch_bounds__(256) void fused_fallback(const float* __restrict__ fwd,
                                                      const float* __restrict__ bwd,
                                                      double* __restrict__ ws) {
    __shared__ double red[4];
    const int idx = blockIdx.x * 256 + threadIdx.x;
    const int x = idx & 127; const int y = (idx >> 7) & 127; const int z = idx >> 14;
    const bool hx = (x < WW - 1), hy = (y < HH - 1), hz = (z < DD - 1);

    double accG = 0.0, accJ = 0.0, accI = 0.0;
    float v[3], ddx[3], ddy[3], ddz[3];
    #pragma unroll
    for (int c = 0; c < 3; c++) {
        const float* p = fwd + c * NN + idx;
        float vv = p[0];
        v[c]   = vv;
        ddx[c] = hx ? (p[1] - vv) : 0.f;
        ddy[c] = hy ? (p[WW] - vv) : 0.f;
        ddz[c] = hz ? (p[HH * WW] - vv) : 0.f;
    }
    float g = 0.f;
    #pragma unroll
    for (int c = 0; c < 3; c++)
        g = fmaf(ddz[c], ddz[c], fmaf(ddy[c], ddy[c], fmaf(ddx[c], ddx[c], g)));
    accG = (double)g;
    if (hx && hy && hz) accJ = (double)jac_term(ddz, ddy, ddx);
    {
        float cz = fminf(fmaxf((float)z + v[0], 0.f), (float)(DD - 1));
        float cy = fminf(fmaxf((float)y + v[1], 0.f), (float)(HH - 1));
        float cx = fminf(fmaxf((float)x + v[2], 0.f), (float)(WW - 1));
        float z0f = floorf(cz), y0f = floorf(cy), x0f = floorf(cx);
        float fz = cz - z0f, fy = cy - y0f, fx = cx - x0f;
        int z0 = (int)z0f, y0 = (int)y0f, x0 = (int)x0f;
        int z1 = min(z0 + 1, DD - 1), y1 = min(y0 + 1, HH - 1), x1 = min(x0 + 1, WW - 1);
        int i000 = (z0 * HH + y0) * WW + x0, i001 = (z0 * HH + y0) * WW + x1;
        int i010 = (z0 * HH + y1) * WW + x0, i011 = (z0 * HH + y1) * WW + x1;
        int i100 = (z1 * HH + y0) * WW + x0, i101 = (z1 * HH + y0) * WW + x1;
        int i110 = (z1 * HH + y1) * WW + x0, i111 = (z1 * HH + y1) * WW + x1;
        float w000 = (1.f - fz) * (1.f - fy) * (1.f - fx);
        float w001 = (1.f - fz) * (1.f - fy) * fx;
        float w010 = (1.f - fz) * fy * (1.f - fx);
        float w011 = (1.f - fz) * fy * fx;
        float w100 = fz * (1.f - fy) * (1.f - fx);
        float w101 = fz * (1.f - fy) * fx;
        float w110 = fz * fy * (1.f - fx);
        float w111 = fz * fy * fx;
        #pragma unroll
        for (int c = 0; c < 3; c++) {
            const float* b = bwd + c * NN;
            float warped = w000 * b[i000] + w001 * b[i001]
                         + w010 * b[i010] + w011 * b[i011]
                         + w100 * b[i100] + w101 * b[i101]
                         + w110 * b[i110] + w111 * b[i111];
            float comp = v[c] + warped;
            accI += (double)(comp * comp);
        }
    }

    double tG = block_reduce<4>(accG, red, threadIdx.x);
    double tJ = block_reduce<4>(accJ, red, threadIdx.x);
    double tI = block_reduce<4>(accI, red, threadIdx.x);
    if (threadIdx.x == 0) {
        ws[GOFF + blockIdx.x] = tG;
        ws[JOFF + blockIdx.x] = tJ;
        ws[IOFF + blockIdx.x] = tI;
    }
}

// ---------- 3) finalize ----------
__global__ __launch_bounds__(256) void finalize_kernel(const double* __restrict__ ws,
                                                       float* __restrict__ out) {
    __shared__ double red[4];
    double l = 0.0, g = 0.0, j = 0.0, inv = 0.0;
    for (int k = threadIdx.x; k < NB_LNCC; k += 256) l += ws[LOFF + k];
    for (int k = threadIdx.x; k < NB_FUSED; k += 256) {
        g   += ws[GOFF + k];
        j   += ws[JOFF + k];
        inv += ws[IOFF + k];
    }
    double tl = block_reduce<4>(l, red, threadIdx.x);
    double tg = block_reduce<4>(g, red, threadIdx.x);
    double tj = block_reduce<4>(j, red, threadIdx.x);
    double ti = block_reduce<4>(inv, red, threadIdx.x);
    if (threadIdx.x == 0) {
        double li = 1.0 - tl / (double)NN;
        if (isnan(li) || isinf(li)) li = 1.0;
        double grad = tg / (9.0 * 127.0 * 128.0 * 128.0);
        double jac  = tj / ((double)DJ * DJ * DJ);
        double iv = ti / (3.0 * (double)NN);
        if (isnan(iv)) iv = 0.0;
        else if (isinf(iv)) iv = iv > 0.0 ? 1000.0 : 0.0;
        out[0] = (float)(1.0 * li + 0.02 * grad + 0.01 * jac + 0.1 * iv);
    }
}

extern "C" void kernel_launch(void* const* d_in, const int* in_sizes, int n_in,
                              void* d_out, int out_size, void* d_ws, size_t ws_size,
                              hipStream_t stream) {
    const float* src = (const float*)d_in[0];
    const float* tgt = (const float*)d_in[1];
    const float* fwd = (const float*)d_in[2];
    const float* bwd = (const float*)d_in[3];
    double* ws = (double*)d_ws;
    float* out = (float*)d_out;

    if (ws_size >= WS_NEED) {
        Half4* bwdh = (Half4*)((char*)d_ws + BWDH_OFF);
        interleave4h_kernel<<<2048, 256, 0, stream>>>(bwd, bwdh);
        lncc_kernel<<<4096, 512, 0, stream>>>(src, tgt, ws);
        fused1h_kernel<<<NB_FUSED, 256, 0, stream>>>(fwd, bwdh, ws);
    } else {
        lncc_kernel<<<4096, 512, 0, stream>>>(src, tgt, ws);
        fused_fallback<<<NB_FUSED, 256, 0, stream>>>(fwd, bwd, ws);
    }
    finalize_kernel<<<1, 256, 0, stream>>>(ws, out);
}

// Round 12
// 83.345 us; speedup vs baseline: 1.2757x; 1.0875x over previous
//
#include <hip/hip_runtime.h>
#include <hip/hip_fp16.h>
#include <math.h>

#define DD 128
#define HH 128
#define WW 128
#define NN (DD*HH*WW)
#define DJ 127

// workspace layout: [slots: doubles][bwd interleaved half4 volume]
#define NB_LNCC 4096
#define NB_FUSED 8192
#define LOFF 0
#define GOFF (NB_LNCC)
#define JOFF (NB_LNCC + NB_FUSED)
#define IOFF (NB_LNCC + 2*NB_FUSED)
#define NSLOTS (NB_LNCC + 3*NB_FUSED)
#define BWDH_OFF ((size_t)((NSLOTS * 8 + 255) & ~255))   // 256B aligned
#define WS_NEED (BWDH_OFF + (size_t)NN * 8)

struct __align__(8)  Half4 { __half x, y, z, w; };
// fp16-packed LNCC moment storage:
struct __align__(16) H8  { __half2 a0, b0, a1, b1; };   // positions 2k,2k+1: (s1,t1),(s2,t2) each
struct __align__(8)  HS4 { __half2 u, v; };             // st for positions 4k..4k+3

// ---------- small helpers ----------
__device__ __forceinline__ double wave_reduce(double v) {
    #pragma unroll
    for (int o = 32; o > 0; o >>= 1) v += __shfl_down(v, o);
    return v;
}

template <int NWAVES>
__device__ __forceinline__ double block_reduce(double v, double* red, int tid) {
    v = wave_reduce(v);
    int wid = tid >> 6, lane = tid & 63;
    __syncthreads();
    if (lane == 0) red[wid] = v;
    __syncthreads();
    double x = 0.0;
    if (tid == 0) {
        #pragma unroll
        for (int w = 0; w < NWAVES; w++) x += red[w];
    }
    return x;
}

__device__ __forceinline__ float jac_term(const float* dz_, const float* dy_, const float* dx_) {
    float a00 = 1.f + dz_[0], a01 = dy_[0], a02 = dx_[0];
    float a10 = dz_[1], a11 = 1.f + dy_[1], a12 = dx_[1];
    float a20 = dz_[2], a21 = dy_[2], a22 = 1.f + dx_[2];
    float det = a00 * (a11 * a22 - a12 * a21)
              - a01 * (a10 * a22 - a12 * a20)
              + a02 * (a10 * a21 - a11 * a20);
    if (isnan(det)) det = 0.f;
    else if (isinf(det)) det = det > 0.f ? 1000.f : -1000.f;
    float neg = -det;
    return neg > 0.f ? neg : 0.f;
}

__device__ __forceinline__ float lncc_val(float S1, float T1, float S2, float T2, float ST) {
    const float inv125 = 1.f / 125.f;
    float sm = S1 * inv125, tm = T1 * inv125;
    float sv = S2 * inv125 - sm * sm;
    float tv = T2 * inv125 - tm * tm;
    float cross = ST * inv125 - sm * tm;
    return cross * cross / (sv * tv + 1e-5f);
}

// ---------- 0) channel-interleave bwd -> half4 bwdh, 4 voxels/thread ----------
__global__ __launch_bounds__(256) void interleave4h_kernel(const float* __restrict__ bwd,
                                                           Half4* __restrict__ bwdh) {
    const int i4 = (blockIdx.x * 256 + threadIdx.x) * 4;
    float4 b0 = *(const float4*)(bwd + i4);
    float4 b1 = *(const float4*)(bwd + NN + i4);
    float4 b2 = *(const float4*)(bwd + 2 * NN + i4);
    Half4 o0 = { __float2half(b0.x), __float2half(b1.x), __float2half(b2.x), __float2half(0.f) };
    Half4 o1 = { __float2half(b0.y), __float2half(b1.y), __float2half(b2.y), __float2half(0.f) };
    Half4 o2 = { __float2half(b0.z), __float2half(b1.z), __float2half(b2.z), __float2half(0.f) };
    Half4 o3 = { __float2half(b0.w), __float2half(b1.w), __float2half(b2.w), __float2half(0.f) };
    bwdh[i4 + 0] = o0;
    bwdh[i4 + 1] = o1;
    bwdh[i4 + 2] = o2;
    bwdh[i4 + 3] = o3;
}

// ---------- 1) LNCC: separable box filter, fp16-packed LDS moments ----------
// 8^3 tile, 256 threads, ~19.2KB LDS -> 8 blocks/CU (was 38.9KB/4 blocks).
// y/z passes read 3 LDS ops per tap instead of 5 b128; adds via __hadd2.
// fp16 moment error ~1e-4 on the final scalar (threshold 2.36e-2).
__global__ __launch_bounds__(256) void lncc_kernel(const float* __restrict__ src,
                                                   const float* __restrict__ tgt,
                                                   double* __restrict__ ws) {
    __shared__ H8  F1A[576];    // x-summed (s1,t1,s2,t2), idx = pos>>1, pos=(lz*12+ly)*8+ox
    __shared__ HS4 F1S[288];    // x-summed st, idx = pos>>2
    __shared__ H8  F2A[384];    // xy-summed, pos=(lz*8+oy)*8+ox
    __shared__ HS4 F2S[192];
    __shared__ double red[4];
    const int tid = threadIdx.x;
    const int slot = (blockIdx.x & 7) * 512 + (blockIdx.x >> 3);   // bijective, 4096%8==0
    const int bz = (slot >> 8) * 8;
    const int by = ((slot >> 4) & 15) * 8;
    const int bx = (slot & 15) * 8;

    // ---- x-pass: 288 half-row tasks (4 outputs each) ----
    for (int t = tid; t < 288; t += 256) {
        const int h = t & 1;
        const int row = t >> 1;
        const int ly = row % 12, lz = row / 12;
        const int gy = by + ly - 2, gz = bz + lz - 2;
        const bool rowok = (gy >= 0 && gy < HH && gz >= 0 && gz < DD);
        const int rowbase = (gz * HH + gy) * WW;
        const int w0 = bx + h * 4 - 4;            // aligned float4 window start

        float4 lsv[3], ltv[3];
        #pragma unroll
        for (int p = 0; p < 3; p++) {
            int gx = w0 + 4 * p;
            if (rowok && gx >= 0 && gx <= WW - 4) {
                lsv[p] = *(const float4*)(src + rowbase + gx);
                ltv[p] = *(const float4*)(tgt + rowbase + gx);
            } else {
                lsv[p] = make_float4(0.f, 0.f, 0.f, 0.f);
                ltv[p] = make_float4(0.f, 0.f, 0.f, 0.f);
            }
        }
        const float* ls = (const float*)lsv;   // 12 values, static-indexed below
        const float* lt = (const float*)ltv;

        float o[5][4];
        #pragma unroll
        for (int k = 0; k < 4; k++) {
            float s1 = 0.f, t1s = 0.f, s2 = 0.f, t2s = 0.f, st = 0.f;
            #pragma unroll
            for (int d = 0; d < 5; d++) {
                float a = ls[k + d + 2], b = lt[k + d + 2];
                s1 += a; t1s += b;
                s2 = fmaf(a, a, s2); t2s = fmaf(b, b, t2s); st = fmaf(a, b, st);
            }
            o[0][k] = s1; o[1][k] = t1s; o[2][k] = s2; o[3][k] = t2s; o[4][k] = st;
        }
        const int obase = (lz * 12 + ly) * 8 + h * 4;   // multiple of 4
        H8 e0 = { __floats2half2_rn(o[0][0], o[1][0]), __floats2half2_rn(o[2][0], o[3][0]),
                  __floats2half2_rn(o[0][1], o[1][1]), __floats2half2_rn(o[2][1], o[3][1]) };
        H8 e1 = { __floats2half2_rn(o[0][2], o[1][2]), __floats2half2_rn(o[2][2], o[3][2]),
                  __floats2half2_rn(o[0][3], o[1][3]), __floats2half2_rn(o[2][3], o[3][3]) };
        F1A[(obase >> 1) + 0] = e0;
        F1A[(obase >> 1) + 1] = e1;
        HS4 es = { __floats2half2_rn(o[4][0], o[4][1]), __floats2half2_rn(o[4][2], o[4][3]) };
        F1S[obase >> 2] = es;
    }
    __syncthreads();

    // ---- y-pass: 192 quad tasks; 3 LDS reads per dy; __hadd2 accumulation ----
    if (tid < 192) {
        const int h = tid & 1;
        const int r = tid >> 1;
        const int oy = r & 7, lz = r >> 3;
        const __half2 z2 = __float2half2_rn(0.f);
        __half2 A0 = z2, B0 = z2, A1 = z2, B1 = z2;   // positions 0,1 of the quad
        __half2 A2 = z2, B2 = z2, A3 = z2, B3 = z2;   // positions 2,3
        __half2 S01 = z2, S23 = z2;
        #pragma unroll
        for (int dy = 0; dy < 5; dy++) {
            const int jb = (lz * 12 + oy + dy) * 8 + h * 4;
            H8 p = F1A[(jb >> 1) + 0];
            H8 q = F1A[(jb >> 1) + 1];
            A0 = __hadd2(A0, p.a0); B0 = __hadd2(B0, p.b0);
            A1 = __hadd2(A1, p.a1); B1 = __hadd2(B1, p.b1);
            A2 = __hadd2(A2, q.a0); B2 = __hadd2(B2, q.b0);
            A3 = __hadd2(A3, q.a1); B3 = __hadd2(B3, q.b1);
            HS4 s = F1S[jb >> 2];
            S01 = __hadd2(S01, s.u); S23 = __hadd2(S23, s.v);
        }
        const int jo = (lz * 8 + oy) * 8 + h * 4;
        H8 w0v = { A0, B0, A1, B1 };
        H8 w1v = { A2, B2, A3, B3 };
        F2A[(jo >> 1) + 0] = w0v;
        F2A[(jo >> 1) + 1] = w1v;
        HS4 wsv = { S01, S23 };
        F2S[jo >> 2] = wsv;
    }
    __syncthreads();

    // ---- z-pass + lncc: 256 tasks x 2 voxels (full lane utilization) ----
    double lsum = 0.0;
    {
        const int pos = tid * 2;                   // even position in 8x8x8 tile
        const int oz = pos >> 6, oy = (pos >> 3) & 7, ox = pos & 7;
        const __half2 z2 = __float2half2_rn(0.f);
        __half2 cA0 = z2, cB0 = z2, cA1 = z2, cB1 = z2, cS = z2;
        #pragma unroll
        for (int dz = 0; dz < 5; dz++) {
            const int j = (((oz + dz) * 8 + oy) * 8) + ox;   // even
            H8 p = F2A[j >> 1];
            cA0 = __hadd2(cA0, p.a0); cB0 = __hadd2(cB0, p.b0);
            cA1 = __hadd2(cA1, p.a1); cB1 = __hadd2(cB1, p.b1);
            HS4 s = F2S[j >> 2];
            cS = __hadd2(cS, (j & 2) ? s.v : s.u);
        }
        float2 s1t1_0 = __half22float2(cA0);
        float2 s2t2_0 = __half22float2(cB0);
        float2 s1t1_1 = __half22float2(cA1);
        float2 s2t2_1 = __half22float2(cB1);
        float2 stp    = __half22float2(cS);
        lsum = (double)lncc_val(s1t1_0.x, s1t1_0.y, s2t2_0.x, s2t2_0.y, stp.x)
             + (double)lncc_val(s1t1_1.x, s1t1_1.y, s2t2_1.x, s2t2_1.y, stp.y);
    }
    double tot = block_reduce<4>(lsum, red, tid);
    if (tid == 0) ws[LOFF + slot] = tot;
}

// ---------- 2) fused grad + jac + inv: 1 voxel/thread, half4 gathers (r11, 35us) ----------
__global__ __launch_bounds__(256, 4) void fused1h_kernel(const float* __restrict__ fwd,
                                                         const Half4* __restrict__ bwdh,
                                                         double* __restrict__ ws) {
    __shared__ double red[4];

    const int swz = (blockIdx.x & 7) * (NB_FUSED / 8) + (blockIdx.x >> 3);  // bijective, 8192%8==0
    const int idx = swz * 256 + threadIdx.x;        // voxel id; z-slab [16*(bid&7),...+16)
    const int x = idx & 127; const int y = (idx >> 7) & 127; const int z = idx >> 14;
    const bool hx = (x < WW - 1), hy = (y < HH - 1), hz = (z < DD - 1);

    double accG = 0.0, accJ = 0.0, accI = 0.0;

    float v[3], ddx[3], ddy[3], ddz[3];
    #pragma unroll
    for (int c = 0; c < 3; c++) {
        const float* p = fwd + c * NN + idx;
        float vv = p[0];
        v[c]   = vv;
        ddx[c] = hx ? (p[1] - vv) : 0.f;
        ddy[c] = hy ? (p[WW] - vv) : 0.f;
        ddz[c] = hz ? (p[HH * WW] - vv) : 0.f;
    }

    {
        float g = 0.f;
        #pragma unroll
        for (int c = 0; c < 3; c++)
            g = fmaf(ddz[c], ddz[c], fmaf(ddy[c], ddy[c], fmaf(ddx[c], ddx[c], g)));
        accG = (double)g;
    }

    if (hx && hy && hz) accJ = (double)jac_term(ddz, ddy, ddx);

    {
        float cz = fminf(fmaxf((float)z + v[0], 0.f), (float)(DD - 1));
        float cy = fminf(fmaxf((float)y + v[1], 0.f), (float)(HH - 1));
        float cx = fminf(fmaxf((float)x + v[2], 0.f), (float)(WW - 1));
        float z0f = floorf(cz), y0f = floorf(cy), x0f = floorf(cx);
        float fz = cz - z0f, fy = cy - y0f, fx = cx - x0f;
        int z0 = (int)z0f, y0 = (int)y0f, x0 = (int)x0f;
        int z1 = min(z0 + 1, DD - 1), y1 = min(y0 + 1, HH - 1), x1 = min(x0 + 1, WW - 1);
        int b00 = (z0 * HH + y0) * WW, b01 = (z0 * HH + y1) * WW;
        int b10 = (z1 * HH + y0) * WW, b11 = (z1 * HH + y1) * WW;
        Half4 H000 = bwdh[b00 + x0], H001 = bwdh[b00 + x1];
        Half4 H010 = bwdh[b01 + x0], H011 = bwdh[b01 + x1];
        Half4 H100 = bwdh[b10 + x0], H101 = bwdh[b10 + x1];
        Half4 H110 = bwdh[b11 + x0], H111 = bwdh[b11 + x1];
        float w000 = (1.f - fz) * (1.f - fy) * (1.f - fx);
        float w001 = (1.f - fz) * (1.f - fy) * fx;
        float w010 = (1.f - fz) * fy * (1.f - fx);
        float w011 = (1.f - fz) * fy * fx;
        float w100 = fz * (1.f - fy) * (1.f - fx);
        float w101 = fz * (1.f - fy) * fx;
        float w110 = fz * fy * (1.f - fx);
        float w111 = fz * fy * fx;
        float c0 = v[0] + w000 * __half2float(H000.x) + w001 * __half2float(H001.x)
                        + w010 * __half2float(H010.x) + w011 * __half2float(H011.x)
                        + w100 * __half2float(H100.x) + w101 * __half2float(H101.x)
                        + w110 * __half2float(H110.x) + w111 * __half2float(H111.x);
        float c1 = v[1] + w000 * __half2float(H000.y) + w001 * __half2float(H001.y)
                        + w010 * __half2float(H010.y) + w011 * __half2float(H011.y)
                        + w100 * __half2float(H100.y) + w101 * __half2float(H101.y)
                        + w110 * __half2float(H110.y) + w111 * __half2float(H111.y);
        float c2 = v[2] + w000 * __half2float(H000.z) + w001 * __half2float(H001.z)
                        + w010 * __half2float(H010.z) + w011 * __half2float(H011.z)
                        + w100 * __half2float(H100.z) + w101 * __half2float(H101.z)
                        + w110 * __half2float(H110.z) + w111 * __half2float(H111.z);
        accI = (double)(c0 * c0 + c1 * c1 + c2 * c2);
    }

    double tG = block_reduce<4>(accG, red, threadIdx.x);
    double tJ = block_reduce<4>(accJ, red, threadIdx.x);
    double tI = block_reduce<4>(accI, red, threadIdx.x);
    if (threadIdx.x == 0) {
        ws[GOFF + swz] = tG;
        ws[JOFF + swz] = tJ;
        ws[IOFF + swz] = tI;
    }
}

// ---------- 2b) fallback: planar scalar gathers (exact fp32) ----------
__global__ __launch_bounds__(256) void fused_fallback(const float* __restrict__ fwd,
                                                      const float* __restrict__ bwd,
                                                      double* __restrict__ ws) {
    __shared__ double red[4];
    const int idx = blockIdx.x * 256 + threadIdx.x;
    const int x = idx & 127; const int y = (idx >> 7) & 127; const int z = idx >> 14;
    const bool hx = (x < WW - 1), hy = (y < HH - 1), hz = (z < DD - 1);

    double accG = 0.0, accJ = 0.0, accI = 0.0;
    float v[3], ddx[3], ddy[3], ddz[3];
    #pragma unroll
    for (int c = 0; c < 3; c++) {
        const float* p = fwd + c * NN + idx;
        float vv = p[0];
        v[c]   = vv;
        ddx[c] = hx ? (p[1] - vv) : 0.f;
        ddy[c] = hy ? (p[WW] - vv) : 0.f;
        ddz[c] = hz ? (p[HH * WW] - vv) : 0.f;
    }
    float g = 0.f;
    #pragma unroll
    for (int c = 0; c < 3; c++)
        g = fmaf(ddz[c], ddz[c], fmaf(ddy[c], ddy[c], fmaf(ddx[c], ddx[c], g)));
    accG = (double)g;
    if (hx && hy && hz) accJ = (double)jac_term(ddz, ddy, ddx);
    {
        float cz = fminf(fmaxf((float)z + v[0], 0.f), (float)(DD - 1));
        float cy = fminf(fmaxf((float)y + v[1], 0.f), (float)(HH - 1));
        float cx = fminf(fmaxf((float)x + v[2], 0.f), (float)(WW - 1));
        float z0f = floorf(cz), y0f = floorf(cy), x0f = floorf(cx);
        float fz = cz - z0f, fy = cy - y0f, fx = cx - x0f;
        int z0 = (int)z0f, y0 = (int)y0f, x0 = (int)x0f;
        int z1 = min(z0 + 1, DD - 1), y1 = min(y0 + 1, HH - 1), x1 = min(x0 + 1, WW - 1);
        int i000 = (z0 * HH + y0) * WW + x0, i001 = (z0 * HH + y0) * WW + x1;
        int i010 = (z0 * HH + y1) * WW + x0, i011 = (z0 * HH + y1) * WW + x1;
        int i100 = (z1 * HH + y0) * WW + x0, i101 = (z1 * HH + y0) * WW + x1;
        int i110 = (z1 * HH + y1) * WW + x0, i111 = (z1 * HH + y1) * WW + x1;
        float w000 = (1.f - fz) * (1.f - fy) * (1.f - fx);
        float w001 = (1.f - fz) * (1.f - fy) * fx;
        float w010 = (1.f - fz) * fy * (1.f - fx);
        float w011 = (1.f - fz) * fy * fx;
        float w100 = fz * (1.f - fy) * (1.f - fx);
        float w101 = fz * (1.f - fy) * fx;
        float w110 = fz * fy * (1.f - fx);
        float w111 = fz * fy * fx;
        #pragma unroll
        for (int c = 0; c < 3; c++) {
            const float* b = bwd + c * NN;
            float warped = w000 * b[i000] + w001 * b[i001]
                         + w010 * b[i010] + w011 * b[i011]
                         + w100 * b[i100] + w101 * b[i101]
                         + w110 * b[i110] + w111 * b[i111];
            float comp = v[c] + warped;
            accI += (double)(comp * comp);
        }
    }

    double tG = block_reduce<4>(accG, red, threadIdx.x);
    double tJ = block_reduce<4>(accJ, red, threadIdx.x);
    double tI = block_reduce<4>(accI, red, threadIdx.x);
    if (threadIdx.x == 0) {
        ws[GOFF + blockIdx.x] = tG;
        ws[JOFF + blockIdx.x] = tJ;
        ws[IOFF + blockIdx.x] = tI;
    }
}

// ---------- 3) finalize ----------
__global__ __launch_bounds__(256) void finalize_kernel(const double* __restrict__ ws,
                                                       float* __restrict__ out) {
    __shared__ double red[4];
    double l = 0.0, g = 0.0, j = 0.0, inv = 0.0;
    for (int k = threadIdx.x; k < NB_LNCC; k += 256) l += ws[LOFF + k];
    for (int k = threadIdx.x; k < NB_FUSED; k += 256) {
        g   += ws[GOFF + k];
        j   += ws[JOFF + k];
        inv += ws[IOFF + k];
    }
    double tl = block_reduce<4>(l, red, threadIdx.x);
    double tg = block_reduce<4>(g, red, threadIdx.x);
    double tj = block_reduce<4>(j, red, threadIdx.x);
    double ti = block_reduce<4>(inv, red, threadIdx.x);
    if (threadIdx.x == 0) {
        double li = 1.0 - tl / (double)NN;
        if (isnan(li) || isinf(li)) li = 1.0;
        double grad = tg / (9.0 * 127.0 * 128.0 * 128.0);
        double jac  = tj / ((double)DJ * DJ * DJ);
        double iv = ti / (3.0 * (double)NN);
        if (isnan(iv)) iv = 0.0;
        else if (isinf(iv)) iv = iv > 0.0 ? 1000.0 : 0.0;
        out[0] = (float)(1.0 * li + 0.02 * grad + 0.01 * jac + 0.1 * iv);
    }
}

extern "C" void kernel_launch(void* const* d_in, const int* in_sizes, int n_in,
                              void* d_out, int out_size, void* d_ws, size_t ws_size,
                              hipStream_t stream) {
    const float* src = (const float*)d_in[0];
    const float* tgt = (const float*)d_in[1];
    const float* fwd = (const float*)d_in[2];
    const float* bwd = (const float*)d_in[3];
    double* ws = (double*)d_ws;
    float* out = (float*)d_out;

    if (ws_size >= WS_NEED) {
        Half4* bwdh = (Half4*)((char*)d_ws + BWDH_OFF);
        interleave4h_kernel<<<2048, 256, 0, stream>>>(bwd, bwdh);
        lncc_kernel<<<4096, 256, 0, stream>>>(src, tgt, ws);
        fused1h_kernel<<<NB_FUSED, 256, 0, stream>>>(fwd, bwdh, ws);
    } else {
        lncc_kernel<<<4096, 256, 0, stream>>>(src, tgt, ws);
        fused_fallback<<<NB_FUSED, 256, 0, stream>>>(fwd, bwd, ws);
    }
    finalize_kernel<<<1, 256, 0, stream>>>(ws, out);
}